// Round 7
// baseline (214.789 us; speedup 1.0000x reference)
//
#include <hip/hip_runtime.h>

#define B_ 4
#define T_ 4096
#define DM 512
#define DH 64
#define CS 256     // s-chunk for k_out
#define CT 512     // t-chunk for k_stats

typedef short short8 __attribute__((ext_vector_type(8)));
typedef short bsh4 __attribute__((ext_vector_type(4)));
typedef float f32x4 __attribute__((ext_vector_type(4)));
typedef float float8 __attribute__((ext_vector_type(8)));

__device__ inline short f2bf(float f) {
    unsigned u = __float_as_uint(f);
    u += 0x7fffu + ((u >> 16) & 1u);
    return (short)(u >> 16);
}
__device__ inline float bf2f(short s) {
    return __uint_as_float(((unsigned)(unsigned short)s) << 16);
}
__device__ inline short8 cvt8s(const float* p, float sc) {
    float8 v = *(const float8*)p;
    short8 r;
#pragma unroll
    for (int j = 0; j < 8; j++) r[j] = f2bf(v[j] * sc);
    return r;
}

// 16x16x16 bf16 MFMA (PV): A = per-lane P frag, B = vT frag
__device__ inline f32x4 mfma16(bsh4 a, bsh4 b, f32x4 c) {
    return __builtin_amdgcn_mfma_f32_16x16x16bf16_1k(a, b, c, 0, 0, 0);
}

// ---------------- Kernel 0: Wq|Wk|Wv (fp32) -> wb (bf16, concat); Wq scaled by 0.125 ----------------
__global__ __launch_bounds__(256) void k_wcvt(
    const float* __restrict__ Wq, const float* __restrict__ Wk,
    const float* __restrict__ Wv, short* __restrict__ wb)
{
    int e = (blockIdx.x * 256 + threadIdx.x) * 8;
    int m = e / (DH * DM);
    int off = e - m * (DH * DM);
    const float* W = (m == 0) ? Wq : (m == 1) ? Wk : Wv;
    float sc = (m == 0) ? 0.125f : 1.0f;
    *(short8*)(wb + e) = cvt8s(W + off, sc);
}

// ---------------- Kernel 1: q,k,v projections; 16-row tiles, x read once ----------------
// grid = B*T/16 = 1024 blocks; each wave: 48 of 192 output cols
__global__ __launch_bounds__(256, 4) void k_proj(
    const float* __restrict__ x, const short* __restrict__ wb,
    short* __restrict__ qb, short* __restrict__ kb, short* __restrict__ vb)
{
    __shared__ short xs[16 * 520];   // 16 rows x (512+8) bf16 = 16.6 KB
    int tid = threadIdx.x;
    int lane = tid & 63, w = tid >> 6;
    int l16 = lane & 15, quad = lane >> 4;
    long R0 = (long)blockIdx.x * 16;

    // stage x tile (fp32 -> bf16), coalesced: 8192 elems = 4 passes x 256 thr x 8
#pragma unroll
    for (int p = 0; p < 4; p++) {
        int idx = p * 256 + tid;
        int row = idx >> 6, colc = idx & 63;
        *(short8*)(xs + row * 520 + colc * 8) = cvt8s(x + (R0 + row) * DM + colc * 8, 1.0f);
    }
    __syncthreads();

    int cb = w * 48;
    const short* Wrow[3];
    int mm[3], hc[3];
#pragma unroll
    for (int i = 0; i < 3; i++) {
        int col0 = cb + i * 16;
        mm[i] = col0 >> 6;
        hc[i] = (col0 & 63) + l16;
        Wrow[i] = wb + mm[i] * DH * DM + (long)hc[i] * DM;
    }

    f32x4 a[3];
#pragma unroll
    for (int i = 0; i < 3; i++) a[i] = (f32x4)(0.f);

    for (int kc = 0; kc < DM; kc += 32) {
        short8 af = *(const short8*)(xs + l16 * 520 + kc + quad * 8);
#pragma unroll
        for (int i = 0; i < 3; i++) {
            short8 bf = *(const short8*)(Wrow[i] + kc + quad * 8);
            a[i] = __builtin_amdgcn_mfma_f32_16x16x32_bf16(af, bf, a[i], 0, 0, 0);
        }
    }
#pragma unroll
    for (int i = 0; i < 3; i++) {
        short* op = (mm[i] == 0) ? qb : (mm[i] == 1) ? kb : vb;
#pragma unroll
        for (int r4 = 0; r4 < 4; r4++)
            op[(R0 + quad * 4 + r4) * DH + hc[i]] = f2bf(a[i][r4]);
    }
}

// ---------------- Kernel 2: column sums l[s] += sum_{t in chunk, t>=s} exp(z) ----------------
// dense balanced grid: 4 * 288 blocks; block = 64 s-rows x 512-t chunk; no barriers
__global__ __launch_bounds__(256, 4) void k_stats(
    const short* __restrict__ qb, const short* __restrict__ kb, float* __restrict__ lsum)
{
    int tid = threadIdx.x;
    int lane = tid & 63, w = tid >> 6;
    int l16 = lane & 15, quad = lane >> 4;
    int b = blockIdx.x / 288;
    int idx = blockIdx.x % 288;
    int st = 0, rem = idx;
    while (true) { int n = 8 - (st >> 3); if (rem < n) break; rem -= n; st++; }
    int chunk = (st >> 3) + rem;
    int c0 = chunk * CT, lim = c0 + CT;
    int s0w = st * 64 + w * 16;
    int tb0 = (c0 > (s0w & ~31)) ? c0 : (s0w & ~31);
    long bq = (long)b * T_ * DH;

    const short8* ka = (const short8*)(kb + bq + (long)(s0w + l16) * DH + quad * 8);
    short8 ka0 = ka[0], ka1 = ka[4];   // A[m=s][k=h]

    float acc[4] = {0.f, 0.f, 0.f, 0.f};
    const short* qbase = qb + bq;
    short8 qA0 = *(const short8*)(qbase + (long)(tb0 + l16) * DH + quad * 8);
    short8 qA1 = *(const short8*)(qbase + (long)(tb0 + l16) * DH + 32 + quad * 8);
    short8 qB0 = *(const short8*)(qbase + (long)(tb0 + 16 + l16) * DH + quad * 8);
    short8 qB1 = *(const short8*)(qbase + (long)(tb0 + 16 + l16) * DH + 32 + quad * 8);

    for (int tb = tb0; tb < lim; tb += 32) {
        int tn = (tb + 32 < lim) ? tb + 32 : tb0;   // safe prefetch addr
        short8 nA0 = *(const short8*)(qbase + (long)(tn + l16) * DH + quad * 8);
        short8 nA1 = *(const short8*)(qbase + (long)(tn + l16) * DH + 32 + quad * 8);
        short8 nB0 = *(const short8*)(qbase + (long)(tn + 16 + l16) * DH + quad * 8);
        short8 nB1 = *(const short8*)(qbase + (long)(tn + 16 + l16) * DH + 32 + quad * 8);

        f32x4 dA = (f32x4)(0.f), dB = (f32x4)(0.f);
        dA = __builtin_amdgcn_mfma_f32_16x16x32_bf16(ka0, qA0, dA, 0, 0, 0);
        dA = __builtin_amdgcn_mfma_f32_16x16x32_bf16(ka1, qA1, dA, 0, 0, 0);
        dB = __builtin_amdgcn_mfma_f32_16x16x32_bf16(ka0, qB0, dB, 0, 0, 0);
        dB = __builtin_amdgcn_mfma_f32_16x16x32_bf16(ka1, qB1, dB, 0, 0, 0);
        int tA = tb + l16, tB = tb + 16 + l16;
#pragma unroll
        for (int r = 0; r < 4; r++) {
            int s = s0w + quad * 4 + r;
            float pA = __expf(dA[r]);
            float pB = __expf(dB[r]);
            acc[r] += ((tA >= s) ? pA : 0.f) + ((tB >= s) ? pB : 0.f);
        }
        qA0 = nA0; qA1 = nA1; qB0 = nB0; qB1 = nB1;
    }
#pragma unroll
    for (int r = 0; r < 4; r++) {
        float v = acc[r];
        v += __shfl_xor(v, 1, 16);
        v += __shfl_xor(v, 2, 16);
        v += __shfl_xor(v, 4, 16);
        v += __shfl_xor(v, 8, 16);
        if (l16 == 0) atomicAdd(&lsum[b * T_ + s0w + quad * 4 + r], v);
    }
}

// ---------------- Kernel 3: vT[b][h][s] = bf16(v[b][s][h] / l[s]) ----------------
__global__ __launch_bounds__(256) void k_vt(
    const short* __restrict__ vb, const float* __restrict__ lsum, short* __restrict__ vT)
{
    __shared__ float tile[64][65];
    int tid = threadIdx.x;
    int b = blockIdx.x >> 6;
    int s0 = (blockIdx.x & 63) * 64;
    int h = tid & 63;
#pragma unroll
    for (int i = 0; i < 16; i++) {
        int s = (tid >> 6) + i * 4;
        tile[s][h] = bf2f(vb[((long)(b * T_ + s0 + s)) * DH + h]);
    }
    __syncthreads();
    int sl = tid & 63;
    float rl = 1.0f / lsum[b * T_ + s0 + sl];
    long ob = (long)b * DH * T_ + s0 + sl;
#pragma unroll
    for (int i = 0; i < 16; i++) {
        int hh = (tid >> 6) + i * 4;
        vT[ob + (long)hh * T_] = f2bf(tile[sl][hh] * rl);
    }
}

// ---------------- Kernel 4: transposed-QK fused score+PV; zero LDS, zero barriers ----------------
// dense balanced grid: 4 * 272 blocks (rt descending = heavy first)
// block covers 128 t-rows (wave: 32), chunk of CS=256 s-cols; atomics into out
__global__ __launch_bounds__(256, 4) void k_out(
    const short* __restrict__ qb, const short* __restrict__ kb,
    const short* __restrict__ vT, float* __restrict__ out)
{
    int tid = threadIdx.x;
    int lane = tid & 63, w = tid >> 6;
    int l16 = lane & 15, quad = lane >> 4;
    int b = blockIdx.x / 272;
    int idx = blockIdx.x % 272;
    int rt = 31, rem = idx;
    while (true) { int n = (rt >> 1) + 1; if (rem < n) break; rem -= n; rt--; }
    int c0 = rem * CS;
    int t0w = rt * 128 + w * 32;                 // wave's 32 t-rows
    int s_end = (c0 + CS < t0w + 32) ? c0 + CS : t0w + 32;
    if (s_end <= c0) return;                     // wave idle (no barriers -> safe)
    int nsub = (s_end - c0 + 15) >> 4;
    long bq = (long)b * T_ * DH;
    long vbase = (long)b * DH * T_;

    const short* qbase = qb + bq;
    short8 aqA0 = *(const short8*)(qbase + (long)(t0w + l16) * DH + quad * 8);
    short8 aqA1 = *(const short8*)(qbase + (long)(t0w + l16) * DH + 32 + quad * 8);
    short8 aqB0 = *(const short8*)(qbase + (long)(t0w + 16 + l16) * DH + quad * 8);
    short8 aqB1 = *(const short8*)(qbase + (long)(t0w + 16 + l16) * DH + 32 + quad * 8);

    f32x4 oA[4], oB[4];
#pragma unroll
    for (int i = 0; i < 4; i++) { oA[i] = (f32x4)(0.f); oB[i] = (f32x4)(0.f); }

    const short* kbase = kb + bq;
    short8 kc0 = *(const short8*)(kbase + (long)(c0 + l16) * DH + quad * 8);
    short8 kc1 = *(const short8*)(kbase + (long)(c0 + l16) * DH + 32 + quad * 8);
    bsh4 vc[4];
#pragma unroll
    for (int h4 = 0; h4 < 4; h4++)
        vc[h4] = *(const bsh4*)(vT + vbase + (long)(h4 * 16 + l16) * T_ + c0 + quad * 4);

    int tA = t0w + l16, tB = t0w + 16 + l16;
    for (int j = 0; j < nsub; j++) {
        int sp = (j + 1 < nsub) ? c0 + (j + 1) * 16 : c0;   // safe prefetch addr
        short8 kn0 = *(const short8*)(kbase + (long)(sp + l16) * DH + quad * 8);
        short8 kn1 = *(const short8*)(kbase + (long)(sp + l16) * DH + 32 + quad * 8);
        bsh4 vn[4];
#pragma unroll
        for (int h4 = 0; h4 < 4; h4++)
            vn[h4] = *(const bsh4*)(vT + vbase + (long)(h4 * 16 + l16) * T_ + sp + quad * 4);

        int s0 = c0 + j * 16;
        f32x4 dA = (f32x4)(0.f), dB = (f32x4)(0.f);
        dA = __builtin_amdgcn_mfma_f32_16x16x32_bf16(kc0, aqA0, dA, 0, 0, 0);
        dA = __builtin_amdgcn_mfma_f32_16x16x32_bf16(kc1, aqA1, dA, 0, 0, 0);
        dB = __builtin_amdgcn_mfma_f32_16x16x32_bf16(kc0, aqB0, dB, 0, 0, 0);
        dB = __builtin_amdgcn_mfma_f32_16x16x32_bf16(kc1, aqB1, dB, 0, 0, 0);

        // D[s][t]: lane holds s = s0+quad*4+r, t = l16 (+16 for group B)
        // == exactly the A-operand frag of mfma_f32_16x16x16: m=t=l16, k=s=quad*4+j
        bsh4 fA, fB;
        int sb = s0 + quad * 4;
#pragma unroll
        for (int r = 0; r < 4; r++) {
            int s = sb + r;
            float pA = __expf(dA[r]);
            float pB = __expf(dB[r]);
            fA[r] = f2bf((s <= tA) ? pA : 0.f);
            fB[r] = f2bf((s <= tB) ? pB : 0.f);
        }
#pragma unroll
        for (int h4 = 0; h4 < 4; h4++) {
            oA[h4] = mfma16(fA, vc[h4], oA[h4]);
            oB[h4] = mfma16(fB, vc[h4], oB[h4]);
        }
        kc0 = kn0; kc1 = kn1;
#pragma unroll
        for (int h4 = 0; h4 < 4; h4++) vc[h4] = vn[h4];
    }

#pragma unroll
    for (int h4 = 0; h4 < 4; h4++)
#pragma unroll
        for (int r = 0; r < 4; r++) {
            atomicAdd(&out[bq + (long)(t0w + quad * 4 + r) * DH + h4 * 16 + l16], oA[h4][r]);
            atomicAdd(&out[bq + (long)(t0w + 16 + quad * 4 + r) * DH + h4 * 16 + l16], oB[h4][r]);
        }
}

extern "C" void kernel_launch(void* const* d_in, const int* in_sizes, int n_in,
                              void* d_out, int out_size, void* d_ws, size_t ws_size,
                              hipStream_t stream) {
    const float* x  = (const float*)d_in[0];
    const float* Wq = (const float*)d_in[1];
    const float* Wk = (const float*)d_in[2];
    const float* Wv = (const float*)d_in[3];
    float* out = (float*)d_out;

    char* ws = (char*)d_ws;
    short* qb   = (short*)(ws);                    // 2 MB  bf16 [B,T,64]  (q pre-scaled by 0.125)
    short* kb   = (short*)(ws + (2l << 20));       // 2 MB  bf16 [B,T,64]
    short* vb   = (short*)(ws + (4l << 20));       // 2 MB  bf16 [B,T,64]
    short* vT   = (short*)(ws + (6l << 20));       // 2 MB  bf16 [B,64,T]  (v/l, transposed)
    short* wb   = (short*)(ws + (8l << 20));       // 192 KB bf16 [3,64,512]
    float* lsum = (float*)(ws + (9l << 20));       // 64 KB fp32 [B,T]

    (void)hipMemsetAsync(out, 0, (size_t)out_size * sizeof(float), stream);
    (void)hipMemsetAsync(lsum, 0, (size_t)(B_ * T_) * sizeof(float), stream);

    k_wcvt<<<dim3(48), dim3(256), 0, stream>>>(Wq, Wk, Wv, wb);
    k_proj<<<dim3(B_ * T_ / 16), dim3(256), 0, stream>>>(x, wb, qb, kb, vb);
    k_stats<<<dim3(4 * 288), dim3(256), 0, stream>>>(qb, kb, lsum);
    k_vt<<<dim3(B_ * T_ / 64), dim3(256), 0, stream>>>(vb, lsum, vT);
    k_out<<<dim3(4 * 272), dim3(256), 0, stream>>>(qb, kb, vT, out);
}